// Round 6
// baseline (300.925 us; speedup 1.0000x reference)
//
#include <hip/hip_runtime.h>
#include <hip/hip_bf16.h>

#define BB 32
#define TT 1024
#define JJ 64
#define DD 256

// ext-vector type for nontemporal stores (__builtin_nontemporal_store rejects
// HIP_vector_type<float,4>*; it needs scalar/ext-vector pointee)
typedef __attribute__((ext_vector_type(4))) float f32x4;
__device__ __forceinline__ void nt_store4(float* addr, float4 v) {
    union { float4 a; f32x4 b; } u;
    u.a = v;
    __builtin_nontemporal_store(u.b, (f32x4*)addr);
}

// ---------- K0: fused prep ----------
// blocks [0,512):   U' = U*w_hu, uw[b,j] = U_j.w_u + b   (wave per (b,j) row)
// blocks [512,1024): hw[b,t] = H_t.w_h                    (wave per 16 t-rows)
__global__ __launch_bounds__(256) void k0_prep(const float* __restrict__ U,
                                               const float* __restrict__ H,
                                               const float* __restrict__ w,
                                               const float* __restrict__ bp,
                                               float* __restrict__ Up,
                                               float* __restrict__ uw,
                                               float* __restrict__ hw) {
    const int wave = threadIdx.x >> 6;
    const int lane = threadIdx.x & 63;
    if (blockIdx.x < 512) {
        const int row = blockIdx.x * 4 + wave;     // (b,j) row in [0, B*J)
        float4 u   = *(const float4*)(U + (size_t)row * DD + lane * 4);
        float4 whu = *(const float4*)(w + 2 * DD + lane * 4);
        float4 wu  = *(const float4*)(w + DD + lane * 4);
        float4 o;
        o.x = u.x * whu.x; o.y = u.y * whu.y; o.z = u.z * whu.z; o.w = u.w * whu.w;
        *(float4*)(Up + (size_t)row * DD + lane * 4) = o;
        float p = fmaf(u.x, wu.x, fmaf(u.y, wu.y, fmaf(u.z, wu.z, u.w * wu.w)));
        #pragma unroll
        for (int m = 32; m >= 1; m >>= 1) p += __shfl_xor(p, m, 64);
        if (lane == 0) uw[row] = p + bp[0];
    } else {
        const int base = (blockIdx.x - 512) * 64 + wave * 16;   // t-row base in [0, B*T)
        float4 wh = *(const float4*)(w + lane * 4);
        float pr[16];
        #pragma unroll
        for (int r = 0; r < 16; ++r) {
            float4 h = *(const float4*)(H + (size_t)(base + r) * DD + lane * 4);
            pr[r] = fmaf(h.x, wh.x, fmaf(h.y, wh.y, fmaf(h.z, wh.z, h.w * wh.w)));
        }
        #pragma unroll
        for (int m = 32; m >= 1; m >>= 1) {
            #pragma unroll
            for (int r = 0; r < 16; ++r) pr[r] += __shfl_xor(pr[r], m, 64);
        }
        if (lane == 0) {
            #pragma unroll
            for (int r = 0; r < 16; ++r) hw[base + r] = pr[r];
        }
    }
}

// ---------- K1: S + softmax_j + c2q + G[0:3D] ----------
// grid: B*(T/32) = 1024 blocks, 512 threads (8 waves, 4 t-rows each).
// LDS = 40KB (Ubuf 64x128 swizzled + Abuf 32x64). K split into two 128-halves.
__global__ __launch_bounds__(512, 6) void k1_main(const float* __restrict__ H,
                                                  const float* __restrict__ U,
                                                  const float* __restrict__ Up,
                                                  const float* __restrict__ uw,
                                                  const float* __restrict__ hw,
                                                  float* __restrict__ m_ws,
                                                  float* __restrict__ G,
                                                  float* __restrict__ c2q_out) {
    __shared__ float lds[10240];               // [0,8192): Ubuf 64x128  [8192,10240): Abuf 32x64
    float* Abuf = lds + 8192;
    const int tid  = threadIdx.x;
    const int lane = tid & 63;                 // j in S phase
    const int wave = __builtin_amdgcn_readfirstlane(tid >> 6);
    const int b    = blockIdx.x >> 5;
    const int t0   = (blockIdx.x & 31) << 5;
    const int r0   = t0 + wave * 4;
    const float* Hb = H  + (size_t)b * TT * DD;
    const float* Ub = Up + (size_t)b * JJ * DD;
    const float* Ug = U  + (size_t)b * JJ * DD;
    const float uwj = uw[b * JJ + lane];       // includes +bias

    float4 pf[4];
    float s0 = 0.f, s1 = 0.f, s2 = 0.f, s3 = 0.f;

    // stage half-tile currently in pf -> Ubuf (row-swizzled)
    #define PF_LOAD(SRC, HBYTE)                                                          \
        { _Pragma("unroll") for (int i = 0; i < 4; ++i) {                                \
            int idx = i * 512 + tid; int row = idx >> 5, q = idx & 31;                   \
            pf[i] = *(const float4*)((const char*)(SRC) + row * 1024 + (HBYTE) + q * 16); } }
    #define PF_STORE()                                                                   \
        { _Pragma("unroll") for (int i = 0; i < 4; ++i) {                                \
            int idx = i * 512 + tid; int row = idx >> 5, q = idx & 31;                   \
            *(float4*)((char*)lds + row * 512 + ((q * 16) ^ ((row & 7) << 4))) = pf[i]; } }

    // ---- P0: stage U' half0 ----
    #pragma unroll
    for (int i = 0; i < 4; ++i) {
        int idx = i * 512 + tid; int row = idx >> 5, q = idx & 31;
        float4 v = *(const float4*)((const char*)Ub + row * 1024 + q * 16);
        *(float4*)((char*)lds + row * 512 + ((q * 16) ^ ((row & 7) << 4))) = v;
    }
    __syncthreads();

    // S-dot over one 128-float half; H loads forced to VMEM (asm-laundered ptrs)
    #define S_HALF(HOFF_F)                                                               \
        { const float* hp0 = Hb + (size_t)(r0 + 0) * DD + (HOFF_F);                      \
          const float* hp1 = Hb + (size_t)(r0 + 1) * DD + (HOFF_F);                      \
          const float* hp2 = Hb + (size_t)(r0 + 2) * DD + (HOFF_F);                      \
          const float* hp3 = Hb + (size_t)(r0 + 3) * DD + (HOFF_F);                      \
          asm volatile("" : "+v"(hp0), "+v"(hp1), "+v"(hp2), "+v"(hp3));                 \
          const char* ur = (const char*)lds + lane * 512;                                \
          const int swz = (lane & 7) << 4;                                               \
          _Pragma("unroll 2") for (int dc = 0; dc < 32; ++dc) {                          \
              float4 u  = *(const float4*)(ur + ((dc * 16) ^ swz));                      \
              float4 x0 = *(const float4*)(hp0 + dc * 4);                                \
              float4 x1 = *(const float4*)(hp1 + dc * 4);                                \
              float4 x2 = *(const float4*)(hp2 + dc * 4);                                \
              float4 x3 = *(const float4*)(hp3 + dc * 4);                                \
              s0 = fmaf(x0.x, u.x, fmaf(x0.y, u.y, fmaf(x0.z, u.z, fmaf(x0.w, u.w, s0))));\
              s1 = fmaf(x1.x, u.x, fmaf(x1.y, u.y, fmaf(x1.z, u.z, fmaf(x1.w, u.w, s1))));\
              s2 = fmaf(x2.x, u.x, fmaf(x2.y, u.y, fmaf(x2.z, u.z, fmaf(x2.w, u.w, s2))));\
              s3 = fmaf(x3.x, u.x, fmaf(x3.y, u.y, fmaf(x3.z, u.z, fmaf(x3.w, u.w, s3))));\
          } }

    // ---- P1: prefetch U' half1; S half0 ----
    PF_LOAD(Ub, 512);
    S_HALF(0);
    __syncthreads();
    // ---- P2: Ubuf <- U' half1 ----
    PF_STORE();
    __syncthreads();

    // ---- P3: prefetch rawU half0; S half1; softmax; A -> LDS ----
    PF_LOAD(Ug, 0);
    S_HALF(128);
    {
        float sv0 = s0 + uwj, sv1 = s1 + uwj, sv2 = s2 + uwj, sv3 = s3 + uwj;
        float m0 = sv0, m1 = sv1, m2 = sv2, m3 = sv3;
        #pragma unroll
        for (int m = 32; m >= 1; m >>= 1) {
            m0 = fmaxf(m0, __shfl_xor(m0, m, 64));
            m1 = fmaxf(m1, __shfl_xor(m1, m, 64));
            m2 = fmaxf(m2, __shfl_xor(m2, m, 64));
            m3 = fmaxf(m3, __shfl_xor(m3, m, 64));
        }
        float p0 = __expf(sv0 - m0), p1 = __expf(sv1 - m1);
        float p2 = __expf(sv2 - m2), p3 = __expf(sv3 - m3);
        float l0 = p0, l1 = p1, l2 = p2, l3 = p3;
        #pragma unroll
        for (int m = 32; m >= 1; m >>= 1) {
            l0 += __shfl_xor(l0, m, 64);
            l1 += __shfl_xor(l1, m, 64);
            l2 += __shfl_xor(l2, m, 64);
            l3 += __shfl_xor(l3, m, 64);
        }
        Abuf[(wave * 4 + 0) * 64 + lane] = p0 * (1.0f / l0);
        Abuf[(wave * 4 + 1) * 64 + lane] = p1 * (1.0f / l1);
        Abuf[(wave * 4 + 2) * 64 + lane] = p2 * (1.0f / l2);
        Abuf[(wave * 4 + 3) * 64 + lane] = p3 * (1.0f / l3);
        if (lane == 0) {
            float4 mm;
            mm.x = m0 + hw[b * TT + r0 + 0];
            mm.y = m1 + hw[b * TT + r0 + 1];
            mm.z = m2 + hw[b * TT + r0 + 2];
            mm.w = m3 + hw[b * TT + r0 + 3];
            *(float4*)(m_ws + b * TT + r0) = mm;
        }
    }
    __syncthreads();
    // ---- P4: Ubuf <- rawU half0 ----
    PF_STORE();
    __syncthreads();

    const size_t Gbase = (size_t)b * TT * 1024;

    // c2q over one half + G/c2q writes for that half's d-range
    #define C2Q_HALF(HOFF_F)                                                             \
        { const int q = lane & 31, rh = lane >> 5;                                       \
          float4 a0 = {0.f,0.f,0.f,0.f}, a1 = {0.f,0.f,0.f,0.f};                         \
          const float* Ar0 = Abuf + (wave * 4 + rh) * 64;                                \
          const float* Ar1 = Ar0 + 128;                                                  \
          _Pragma("unroll 2") for (int j = 0; j < 64; ++j) {                             \
              float4 u = *(const float4*)((const char*)lds + j * 512 +                   \
                                          ((q * 16) ^ ((j & 7) << 4)));                  \
              float w0 = Ar0[j], w1 = Ar1[j];                                            \
              a0.x = fmaf(w0, u.x, a0.x); a0.y = fmaf(w0, u.y, a0.y);                    \
              a0.z = fmaf(w0, u.z, a0.z); a0.w = fmaf(w0, u.w, a0.w);                    \
              a1.x = fmaf(w1, u.x, a1.x); a1.y = fmaf(w1, u.y, a1.y);                    \
              a1.z = fmaf(w1, u.z, a1.z); a1.w = fmaf(w1, u.w, a1.w);                    \
          }                                                                              \
          _Pragma("unroll") for (int k = 0; k < 2; ++k) {                                \
              const int row = r0 + rh + 2 * k;                                           \
              float4 c = k ? a1 : a0;                                                    \
              float4 h4 = *(const float4*)(Hb + (size_t)row * DD + (HOFF_F) + q * 4);    \
              float4 hc; hc.x = h4.x * c.x; hc.y = h4.y * c.y;                           \
              hc.z = h4.z * c.z; hc.w = h4.w * c.w;                                      \
              float* Grow = G + Gbase + (size_t)row * 1024 + (HOFF_F) + q * 4;           \
              nt_store4(Grow,       h4);                                                 \
              nt_store4(Grow + 256, c);                                                  \
              nt_store4(Grow + 512, hc);                                                 \
              nt_store4(c2q_out + ((size_t)b * TT + row) * DD + (HOFF_F) + q * 4, c);    \
          } }

    // ---- P5: prefetch rawU half1; c2q half0 + writes ----
    PF_LOAD(Ug, 512);
    C2Q_HALF(0);
    __syncthreads();
    // ---- P6: Ubuf <- rawU half1 ----
    PF_STORE();
    __syncthreads();
    // ---- P7: c2q half1 + writes ----
    C2Q_HALF(128);

    #undef PF_LOAD
    #undef PF_STORE
    #undef S_HALF
    #undef C2Q_HALF
}

// ---------- K2: per-batch softmax over t of m; write wt; zero q2c ----------
__global__ __launch_bounds__(256) void k2_batt(const float* __restrict__ m_ws,
                                               float* __restrict__ wt,
                                               float* __restrict__ q2c_out) {
    __shared__ float red[256];
    const int b = blockIdx.x, tid = threadIdx.x;
    float v0 = m_ws[b * TT + tid];
    float v1 = m_ws[b * TT + 256 + tid];
    float v2 = m_ws[b * TT + 512 + tid];
    float v3 = m_ws[b * TT + 768 + tid];
    red[tid] = fmaxf(fmaxf(v0, v1), fmaxf(v2, v3));
    __syncthreads();
    for (int s = 128; s >= 1; s >>= 1) {
        if (tid < s) red[tid] = fmaxf(red[tid], red[tid + s]);
        __syncthreads();
    }
    const float M = red[0];
    __syncthreads();
    float e0 = __expf(v0 - M), e1 = __expf(v1 - M), e2 = __expf(v2 - M), e3 = __expf(v3 - M);
    red[tid] = e0 + e1 + e2 + e3;
    __syncthreads();
    for (int s = 128; s >= 1; s >>= 1) {
        if (tid < s) red[tid] += red[tid + s];
        __syncthreads();
    }
    const float iz = 1.0f / red[0];
    wt[b * TT + tid]       = e0 * iz;
    wt[b * TT + 256 + tid] = e1 * iz;
    wt[b * TT + 512 + tid] = e2 * iz;
    wt[b * TT + 768 + tid] = e3 * iz;
    q2c_out[b * DD + tid] = 0.0f;              // zero for K2b atomics
}

// ---------- K2b: q2c[b,d] partial sums + atomicAdd; 1024 blocks ----------
__global__ __launch_bounds__(256) void k2b_q2c(const float* __restrict__ H,
                                               const float* __restrict__ wt,
                                               float* __restrict__ q2c_out) {
    const int b = blockIdx.x >> 5, c = blockIdx.x & 31, tid = threadIdx.x;
    const float* Hb = H + ((size_t)b * TT + c * 32) * DD;
    const float* wb = wt + b * TT + c * 32;
    asm volatile("" : "+v"(wb));               // force VMEM (broadcast), not s_load
    float acc = 0.f;
    #pragma unroll 8
    for (int i = 0; i < 32; ++i) acc = fmaf(wb[i], Hb[(size_t)i * DD + tid], acc);
    atomicAdd(&q2c_out[b * DD + tid], acc);
}

// ---------- K3: G[:, :, 3D:4D] = H * q2c ----------
__global__ __launch_bounds__(256) void k3_gtail(const float* __restrict__ H,
                                                const float* __restrict__ q2c,
                                                float* __restrict__ G) {
    const size_t idx = (size_t)blockIdx.x * 256 + threadIdx.x;  // float4 index
    const int d4 = (int)(idx & 63);
    const size_t bt = idx >> 6;
    const int b = (int)(bt >> 10);
    float4 h = *(const float4*)(H + idx * 4);
    float4 q = *(const float4*)(q2c + (size_t)b * DD + d4 * 4);
    float4 o;
    o.x = h.x * q.x; o.y = h.y * q.y; o.z = h.z * q.z; o.w = h.w * q.w;
    nt_store4(G + bt * 1024 + 768 + d4 * 4, o);
}

extern "C" void kernel_launch(void* const* d_in, const int* in_sizes, int n_in,
                              void* d_out, int out_size, void* d_ws, size_t ws_size,
                              hipStream_t stream) {
    const float* U  = (const float*)d_in[0];
    const float* H  = (const float*)d_in[1];
    const float* w  = (const float*)d_in[2];
    const float* bp = (const float*)d_in[3];
    float* out = (float*)d_out;

    // output layout: G (B,T,4D) | c2q (B,T,D) | q2c (B,1,D)
    float* G       = out;
    float* c2q_out = out + (size_t)BB * TT * 4 * DD;
    float* q2c_out = c2q_out + (size_t)BB * TT * DD;

    // workspace (floats): Up | uw | m | wt | hw
    float* Up   = (float*)d_ws;
    float* uwp  = Up + (size_t)BB * JJ * DD;   // 524288
    float* m_ws = uwp + BB * JJ;               // +2048
    float* wtp  = m_ws + BB * TT;              // +32768
    float* hwp  = wtp + BB * TT;               // +32768

    k0_prep<<<1024, 256, 0, stream>>>(U, H, w, bp, Up, uwp, hwp);
    k1_main<<<BB * (TT / 32), 512, 0, stream>>>(H, U, Up, uwp, hwp, m_ws, G, c2q_out);
    k2_batt<<<BB, 256, 0, stream>>>(m_ws, wtp, q2c_out);
    k2b_q2c<<<BB * 32, 256, 0, stream>>>(H, wtp, q2c_out);
    k3_gtail<<<BB * TT * DD / 4 / 256, 256, 0, stream>>>(H, q2c_out, G);
}

// Round 7
// 264.315 us; speedup vs baseline: 1.1385x; 1.1385x over previous
//
#include <hip/hip_runtime.h>
#include <hip/hip_bf16.h>

#define BB 32
#define TT 1024
#define JJ 64
#define DD 256

// ---------- K0: fused prep ----------
// blocks [0,512):   uw[b,j] = U_j.w_u + b   (wave per (b,j) row)
// blocks [512,1024): hw[b,t] = H_t.w_h      (wave per 16 t-rows)
__global__ __launch_bounds__(256) void k0_prep(const float* __restrict__ U,
                                               const float* __restrict__ H,
                                               const float* __restrict__ w,
                                               const float* __restrict__ bp,
                                               float* __restrict__ uw,
                                               float* __restrict__ hw) {
    const int wave = threadIdx.x >> 6;
    const int lane = threadIdx.x & 63;
    if (blockIdx.x < 512) {
        const int row = blockIdx.x * 4 + wave;     // (b,j) row in [0, B*J)
        float4 u  = *(const float4*)(U + (size_t)row * DD + lane * 4);
        float4 wu = *(const float4*)(w + DD + lane * 4);
        float p = fmaf(u.x, wu.x, fmaf(u.y, wu.y, fmaf(u.z, wu.z, u.w * wu.w)));
        #pragma unroll
        for (int m = 32; m >= 1; m >>= 1) p += __shfl_xor(p, m, 64);
        if (lane == 0) uw[row] = p + bp[0];
    } else {
        const int base = (blockIdx.x - 512) * 64 + wave * 16;   // t-row base in [0, B*T)
        float4 wh = *(const float4*)(w + lane * 4);
        float pr[16];
        #pragma unroll
        for (int r = 0; r < 16; ++r) {
            float4 h = *(const float4*)(H + (size_t)(base + r) * DD + lane * 4);
            pr[r] = fmaf(h.x, wh.x, fmaf(h.y, wh.y, fmaf(h.z, wh.z, h.w * wh.w)));
        }
        #pragma unroll
        for (int m = 32; m >= 1; m >>= 1) {
            #pragma unroll
            for (int r = 0; r < 16; ++r) pr[r] += __shfl_xor(pr[r], m, 64);
        }
        if (lane == 0) {
            #pragma unroll
            for (int r = 0; r < 16; ++r) hw[base + r] = pr[r];
        }
    }
}

// ---------- K1: S + softmax_j + c2q + G[0:3D] ----------
// grid: B*(T/32) = 1024 blocks, 512 threads (8 waves, 4 t-rows each).
// LDS 73KB: Ubuf[64][128] swizzled (raw U, K-half) | Hs[32][256] | A[32][64] | whu[256]
// NO global loads in inner loops: H panel + w_hu staged in LDS; U' = U*w_hu
// computed in registers, so one raw-U buffer serves both S and c2q phases.
// c2q runs halves in (h1, h0) order to reuse the staged half from S.
__global__ __launch_bounds__(512, 4) void k1_main(const float* __restrict__ H,
                                                  const float* __restrict__ U,
                                                  const float* __restrict__ uw,
                                                  const float* __restrict__ hw,
                                                  const float* __restrict__ w,
                                                  float* __restrict__ m_ws,
                                                  float* __restrict__ G,
                                                  float* __restrict__ c2q_out) {
    __shared__ float lds[18688];
    float* Hs   = lds + 8192;                  // [32][256]
    float* Abuf = lds + 16384;                 // [32][64]
    float* whuS = lds + 18432;                 // [256]
    const int tid  = threadIdx.x;
    const int lane = tid & 63;                 // j in S phase
    const int wave = __builtin_amdgcn_readfirstlane(tid >> 6);
    const int b    = blockIdx.x >> 5;
    const int t0   = (blockIdx.x & 31) << 5;
    const int r0   = t0 + wave * 4;
    const float* Hb = H + (size_t)b * TT * DD;
    const float* Ug = U + (size_t)b * JJ * DD;
    const float uwj = uw[b * JJ + lane];       // includes +bias

    float4 pf[4];
    float s0 = 0.f, s1 = 0.f, s2 = 0.f, s3 = 0.f;

    #define PF_LOAD(HBYTE)                                                               \
        { _Pragma("unroll") for (int i = 0; i < 4; ++i) {                                \
            int idx = i * 512 + tid; int row = idx >> 5, q = idx & 31;                   \
            pf[i] = *(const float4*)((const char*)Ug + row * 1024 + (HBYTE) + q * 16); } }
    #define PF_STORE()                                                                   \
        { _Pragma("unroll") for (int i = 0; i < 4; ++i) {                                \
            int idx = i * 512 + tid; int row = idx >> 5, q = idx & 31;                   \
            *(float4*)((char*)lds + row * 512 + ((q * 16) ^ ((row & 7) << 4))) = pf[i]; } }

    // ---- P0: stage raw-U half0 (swizzled), H panel, whu table ----
    #pragma unroll
    for (int i = 0; i < 4; ++i) {
        int idx = i * 512 + tid; int row = idx >> 5, q = idx & 31;
        float4 v = *(const float4*)((const char*)Ug + row * 1024 + q * 16);
        *(float4*)((char*)lds + row * 512 + ((q * 16) ^ ((row & 7) << 4))) = v;
    }
    #pragma unroll
    for (int i = 0; i < 4; ++i) {
        int idx = i * 512 + tid; int row = idx >> 6, c = idx & 63;
        float4 v = *(const float4*)(Hb + (size_t)(t0 + row) * DD + c * 4);
        *(float4*)(Hs + row * 256 + c * 4) = v;
    }
    if (tid < 64) *(float4*)(whuS + tid * 4) = *(const float4*)(w + 2 * DD + tid * 4);
    __syncthreads();

    // S-dot over one 128-float half: all operands from LDS/registers.
    // u' = u_raw * whu (regs); h broadcast from Hs.
    #define S_HALF(HOFF_B)                                                               \
        { const char* ur  = (const char*)lds + lane * 512;                               \
          const int   swz = (lane & 7) << 4;                                             \
          const char* hs  = (const char*)Hs + wave * 4096 + (HOFF_B);                    \
          const char* wvp = (const char*)whuS + (HOFF_B);                                \
          _Pragma("unroll 2") for (int dc = 0; dc < 32; ++dc) {                          \
              float4 ua = *(const float4*)(ur + ((dc * 16) ^ swz));                      \
              float4 wv = *(const float4*)(wvp + dc * 16);                               \
              float4 u; u.x = ua.x * wv.x; u.y = ua.y * wv.y;                            \
              u.z = ua.z * wv.z; u.w = ua.w * wv.w;                                      \
              float4 x0 = *(const float4*)(hs + dc * 16);                                \
              float4 x1 = *(const float4*)(hs + 1024 + dc * 16);                         \
              float4 x2 = *(const float4*)(hs + 2048 + dc * 16);                         \
              float4 x3 = *(const float4*)(hs + 3072 + dc * 16);                         \
              s0 = fmaf(x0.x, u.x, fmaf(x0.y, u.y, fmaf(x0.z, u.z, fmaf(x0.w, u.w, s0))));\
              s1 = fmaf(x1.x, u.x, fmaf(x1.y, u.y, fmaf(x1.z, u.z, fmaf(x1.w, u.w, s1))));\
              s2 = fmaf(x2.x, u.x, fmaf(x2.y, u.y, fmaf(x2.z, u.z, fmaf(x2.w, u.w, s2))));\
              s3 = fmaf(x3.x, u.x, fmaf(x3.y, u.y, fmaf(x3.z, u.z, fmaf(x3.w, u.w, s3))));\
          } }

    // ---- P1: prefetch U half1; S half0 ----
    PF_LOAD(512);
    S_HALF(0);
    __syncthreads();
    // ---- P2: Ubuf <- U half1 ----
    PF_STORE();
    __syncthreads();

    // ---- P3: S half1; softmax; A -> LDS ----
    S_HALF(512);
    {
        float sv0 = s0 + uwj, sv1 = s1 + uwj, sv2 = s2 + uwj, sv3 = s3 + uwj;
        float m0 = sv0, m1 = sv1, m2 = sv2, m3 = sv3;
        #pragma unroll
        for (int m = 32; m >= 1; m >>= 1) {
            m0 = fmaxf(m0, __shfl_xor(m0, m, 64));
            m1 = fmaxf(m1, __shfl_xor(m1, m, 64));
            m2 = fmaxf(m2, __shfl_xor(m2, m, 64));
            m3 = fmaxf(m3, __shfl_xor(m3, m, 64));
        }
        float p0 = __expf(sv0 - m0), p1 = __expf(sv1 - m1);
        float p2 = __expf(sv2 - m2), p3 = __expf(sv3 - m3);
        float l0 = p0, l1 = p1, l2 = p2, l3 = p3;
        #pragma unroll
        for (int m = 32; m >= 1; m >>= 1) {
            l0 += __shfl_xor(l0, m, 64);
            l1 += __shfl_xor(l1, m, 64);
            l2 += __shfl_xor(l2, m, 64);
            l3 += __shfl_xor(l3, m, 64);
        }
        Abuf[(wave * 4 + 0) * 64 + lane] = p0 * (1.0f / l0);
        Abuf[(wave * 4 + 1) * 64 + lane] = p1 * (1.0f / l1);
        Abuf[(wave * 4 + 2) * 64 + lane] = p2 * (1.0f / l2);
        Abuf[(wave * 4 + 3) * 64 + lane] = p3 * (1.0f / l3);
        if (lane == 0) {
            float4 mm;
            mm.x = m0 + hw[b * TT + r0 + 0];
            mm.y = m1 + hw[b * TT + r0 + 1];
            mm.z = m2 + hw[b * TT + r0 + 2];
            mm.w = m3 + hw[b * TT + r0 + 3];
            *(float4*)(m_ws + b * TT + r0) = mm;
        }
    }
    __syncthreads();                           // A visible; Ubuf still holds half1

    const size_t Gbase = (size_t)b * TT * 1024;

    // c2q over the d-half currently staged in Ubuf + G/c2q writes for it.
    // h4 comes from Hs (LDS), not global.
    #define C2Q_HALF(HOFF_B, HOFF_F)                                                     \
        { const int q = lane & 31, rh = lane >> 5;                                       \
          float4 a0 = {0.f,0.f,0.f,0.f}, a1 = {0.f,0.f,0.f,0.f};                         \
          const float* Ar0 = Abuf + (wave * 4 + rh) * 64;                                \
          const float* Ar1 = Ar0 + 128;                                                  \
          _Pragma("unroll 2") for (int j = 0; j < 64; ++j) {                             \
              float4 u = *(const float4*)((const char*)lds + j * 512 +                   \
                                          ((q * 16) ^ ((j & 7) << 4)));                  \
              float w0 = Ar0[j], w1 = Ar1[j];                                            \
              a0.x = fmaf(w0, u.x, a0.x); a0.y = fmaf(w0, u.y, a0.y);                    \
              a0.z = fmaf(w0, u.z, a0.z); a0.w = fmaf(w0, u.w, a0.w);                    \
              a1.x = fmaf(w1, u.x, a1.x); a1.y = fmaf(w1, u.y, a1.y);                    \
              a1.z = fmaf(w1, u.z, a1.z); a1.w = fmaf(w1, u.w, a1.w);                    \
          }                                                                              \
          _Pragma("unroll") for (int k = 0; k < 2; ++k) {                                \
              const int lr  = wave * 4 + rh + 2 * k;                                     \
              const int row = t0 + lr;                                                   \
              float4 c = k ? a1 : a0;                                                    \
              float4 h4 = *(const float4*)((const char*)Hs + lr * 1024 +                 \
                                           (HOFF_B) + q * 16);                           \
              float4 hc; hc.x = h4.x * c.x; hc.y = h4.y * c.y;                           \
              hc.z = h4.z * c.z; hc.w = h4.w * c.w;                                      \
              float* Grow = G + Gbase + (size_t)row * 1024 + (HOFF_F) + q * 4;           \
              *(float4*)(Grow)       = h4;                                               \
              *(float4*)(Grow + 256) = c;                                                \
              *(float4*)(Grow + 512) = hc;                                               \
              *(float4*)(c2q_out + ((size_t)b * TT + row) * DD + (HOFF_F) + q * 4) = c;  \
          } }

    // ---- P4: prefetch U half0; c2q d-half1 (Ubuf has half1) + writes ----
    PF_LOAD(0);
    C2Q_HALF(512, 128);
    __syncthreads();
    // ---- P5: Ubuf <- U half0 ----
    PF_STORE();
    __syncthreads();
    // ---- P6: c2q d-half0 + writes ----
    C2Q_HALF(0, 0);

    #undef PF_LOAD
    #undef PF_STORE
    #undef S_HALF
    #undef C2Q_HALF
}

// ---------- K2: per-batch softmax over t of m; write wt; zero q2c ----------
__global__ __launch_bounds__(256) void k2_batt(const float* __restrict__ m_ws,
                                               float* __restrict__ wt,
                                               float* __restrict__ q2c_out) {
    __shared__ float red[256];
    const int b = blockIdx.x, tid = threadIdx.x;
    float v0 = m_ws[b * TT + tid];
    float v1 = m_ws[b * TT + 256 + tid];
    float v2 = m_ws[b * TT + 512 + tid];
    float v3 = m_ws[b * TT + 768 + tid];
    red[tid] = fmaxf(fmaxf(v0, v1), fmaxf(v2, v3));
    __syncthreads();
    for (int s = 128; s >= 1; s >>= 1) {
        if (tid < s) red[tid] = fmaxf(red[tid], red[tid + s]);
        __syncthreads();
    }
    const float M = red[0];
    __syncthreads();
    float e0 = __expf(v0 - M), e1 = __expf(v1 - M), e2 = __expf(v2 - M), e3 = __expf(v3 - M);
    red[tid] = e0 + e1 + e2 + e3;
    __syncthreads();
    for (int s = 128; s >= 1; s >>= 1) {
        if (tid < s) red[tid] += red[tid + s];
        __syncthreads();
    }
    const float iz = 1.0f / red[0];
    wt[b * TT + tid]       = e0 * iz;
    wt[b * TT + 256 + tid] = e1 * iz;
    wt[b * TT + 512 + tid] = e2 * iz;
    wt[b * TT + 768 + tid] = e3 * iz;
    q2c_out[b * DD + tid] = 0.0f;              // zero for K2b atomics
}

// ---------- K2b: q2c[b,d] partial sums + atomicAdd; 1024 blocks ----------
__global__ __launch_bounds__(256) void k2b_q2c(const float* __restrict__ H,
                                               const float* __restrict__ wt,
                                               float* __restrict__ q2c_out) {
    const int b = blockIdx.x >> 5, c = blockIdx.x & 31, tid = threadIdx.x;
    const float* Hb = H + ((size_t)b * TT + c * 32) * DD;
    const float* wb = wt + b * TT + c * 32;
    asm volatile("" : "+v"(wb));               // force VMEM (broadcast), not s_load
    float acc = 0.f;
    #pragma unroll 8
    for (int i = 0; i < 32; ++i) acc = fmaf(wb[i], Hb[(size_t)i * DD + tid], acc);
    atomicAdd(&q2c_out[b * DD + tid], acc);
}

// ---------- K3: G[:, :, 3D:4D] = H * q2c ----------
__global__ __launch_bounds__(256) void k3_gtail(const float* __restrict__ H,
                                                const float* __restrict__ q2c,
                                                float* __restrict__ G) {
    const size_t idx = (size_t)blockIdx.x * 256 + threadIdx.x;  // float4 index
    const int d4 = (int)(idx & 63);
    const size_t bt = idx >> 6;
    const int b = (int)(bt >> 10);
    float4 h = *(const float4*)(H + idx * 4);
    float4 q = *(const float4*)(q2c + (size_t)b * DD + d4 * 4);
    float4 o;
    o.x = h.x * q.x; o.y = h.y * q.y; o.z = h.z * q.z; o.w = h.w * q.w;
    *(float4*)(G + bt * 1024 + 768 + d4 * 4) = o;
}

extern "C" void kernel_launch(void* const* d_in, const int* in_sizes, int n_in,
                              void* d_out, int out_size, void* d_ws, size_t ws_size,
                              hipStream_t stream) {
    const float* U  = (const float*)d_in[0];
    const float* H  = (const float*)d_in[1];
    const float* w  = (const float*)d_in[2];
    const float* bp = (const float*)d_in[3];
    float* out = (float*)d_out;

    // output layout: G (B,T,4D) | c2q (B,T,D) | q2c (B,1,D)
    float* G       = out;
    float* c2q_out = out + (size_t)BB * TT * 4 * DD;
    float* q2c_out = c2q_out + (size_t)BB * TT * DD;

    // workspace (floats): uw | m | wt | hw
    float* uwp  = (float*)d_ws;
    float* m_ws = uwp + BB * JJ;               // +2048
    float* wtp  = m_ws + BB * TT;              // +32768
    float* hwp  = wtp + BB * TT;               // +32768

    k0_prep<<<1024, 256, 0, stream>>>(U, H, w, bp, uwp, hwp);
    k1_main<<<BB * (TT / 32), 512, 0, stream>>>(H, U, uwp, hwp, w, m_ws, G, c2q_out);
    k2_batt<<<BB, 256, 0, stream>>>(m_ws, wtp, q2c_out);
    k2b_q2c<<<BB * 32, 256, 0, stream>>>(H, wtp, q2c_out);
    k3_gtail<<<BB * TT * DD / 4 / 256, 256, 0, stream>>>(H, q2c_out, G);
}